// Round 2
// baseline (3453.505 us; speedup 1.0000x reference)
//
#include <hip/hip_runtime.h>
#include <math.h>

#define HWSZ (512*512)

// ---------------------------------------------------------------------------
// Generic 3x3 conv (pad=1) + bias + PReLU, direct, fp32, single batch.
// Block 256 threads = CG co-groups x PG pixel-groups; each thread computes
// PX_T consecutive-x pixels for CO_T output channels.
// ---------------------------------------------------------------------------
template<int CIN, int COUT, int CHUNK, int TW, int TH, int CO_T, int PX_T>
__global__ __launch_bounds__(256)
void conv3x3_prelu(const float* __restrict__ in, const float* __restrict__ wgt,
                   const float* __restrict__ bias, const float* __restrict__ alpha,
                   float* __restrict__ out)
{
    constexpr int CG  = COUT / CO_T;
    constexpr int PG  = 256 / CG;
    static_assert(PG * PX_T == TW * TH, "tile mismatch");
    constexpr int IW  = TW + 2;
    constexpr int IWP = TW + 3;   // +1 pad breaks LDS bank aliasing
    constexpr int IH  = TH + 2;

    __shared__ __align__(16) float s_in[CHUNK][IH][IWP];
    __shared__ __align__(16) float s_w[CHUNK][9][COUT];

    const int tid = threadIdx.x;
    const int cg  = tid / PG;
    const int pg  = tid % PG;
    const int pl  = pg * PX_T;
    const int ty  = pl / TW;
    const int tx  = pl % TW;
    const int tileX = blockIdx.x * TW;
    const int tileY = blockIdx.y * TH;

    float acc[PX_T][CO_T];
    #pragma unroll
    for (int p = 0; p < PX_T; ++p)
        #pragma unroll
        for (int i = 0; i < CO_T; ++i) acc[p][i] = 0.f;

    for (int c0 = 0; c0 < CIN; c0 += CHUNK) {
        // ---- stage input tile (with zero halo) ----
        for (int idx = tid; idx < CHUNK * IH * IW; idx += 256) {
            int ci = idx / (IH * IW);
            int r  = idx % (IH * IW);
            int iy = r / IW, ix = r % IW;
            int gy = tileY + iy - 1, gx = tileX + ix - 1;
            float v = 0.f;
            if ((unsigned)gy < 512u && (unsigned)gx < 512u)
                v = in[(size_t)(c0 + ci) * HWSZ + gy * 512 + gx];
            s_in[ci][iy][ix] = v;
        }
        // ---- stage weights: layout [ci][tap][co], OIHW source ----
        for (int idx = tid; idx < CHUNK * 9 * COUT; idx += 256) {
            int ci  = idx / (9 * COUT);
            int r   = idx % (9 * COUT);
            int tap = r / COUT, co = r % COUT;
            s_w[ci][tap][co] = wgt[((size_t)co * CIN + (c0 + ci)) * 9 + tap];
        }
        __syncthreads();

        #pragma unroll 1        // keep code size < I-cache
        for (int ci = 0; ci < CHUNK; ++ci) {
            #pragma unroll
            for (int tap = 0; tap < 9; ++tap) {
                const int dy = tap / 3, dx = tap % 3;
                float iv[PX_T];
                #pragma unroll
                for (int p = 0; p < PX_T; ++p) iv[p] = s_in[ci][ty + dy][tx + dx + p];
                #pragma unroll
                for (int i = 0; i < CO_T; i += 4) {
                    const float4 wv = *(const float4*)&s_w[ci][tap][cg * CO_T + i];
                    #pragma unroll
                    for (int p = 0; p < PX_T; ++p) {
                        acc[p][i + 0] = fmaf(iv[p], wv.x, acc[p][i + 0]);
                        acc[p][i + 1] = fmaf(iv[p], wv.y, acc[p][i + 1]);
                        acc[p][i + 2] = fmaf(iv[p], wv.z, acc[p][i + 2]);
                        acc[p][i + 3] = fmaf(iv[p], wv.w, acc[p][i + 3]);
                    }
                }
            }
        }
        __syncthreads();
    }

    // ---- epilogue: bias + PReLU + coalesced float4 stores ----
    const float a  = alpha[0];
    const int  gy  = tileY + ty;
    const int  gx  = tileX + tx;
    #pragma unroll
    for (int i = 0; i < CO_T; ++i) {
        const int co = cg * CO_T + i;
        const float bs = bias[co];
        float4 o;
        float t;
        t = acc[0][i] + bs; o.x = t > 0.f ? t : a * t;
        t = acc[1][i] + bs; o.y = t > 0.f ? t : a * t;
        t = acc[2][i] + bs; o.z = t > 0.f ? t : a * t;
        t = acc[3][i] + bs; o.w = t > 0.f ? t : a * t;
        *(float4*)&out[((size_t)co) * HWSZ + gy * 512 + gx] = o;
    }
}

// ---------------------------------------------------------------------------
// Fused 3-head conv 32->4 (+bias) with GAP partial reduction (atomicAdd).
// Single batch (b passed as arg). Writes raw h planes [head][b][c][H][W].
// ---------------------------------------------------------------------------
__global__ __launch_bounds__(256)
void head_conv(const float* __restrict__ body,
               const float* __restrict__ w1, const float* __restrict__ w2,
               const float* __restrict__ w3,
               const float* __restrict__ b1, const float* __restrict__ b2,
               const float* __restrict__ b3,
               float* __restrict__ h, float* __restrict__ g, int b)
{
    constexpr int TW = 32, TH = 32, CHUNK = 8, CIN = 32, COUT = 12;
    constexpr int IW = TW + 2, IWP = TW + 3, IH = TH + 2;
    __shared__ __align__(16) float s_in[CHUNK][IH][IWP];
    __shared__ __align__(16) float s_w[CHUNK][9][COUT];
    __shared__ float s_red[4][12];

    const int tid = threadIdx.x;
    const int ty  = tid >> 3;
    const int tx  = (tid & 7) << 2;
    const int tileX = blockIdx.x * TW;
    const int tileY = blockIdx.y * TH;

    float acc[4][12];
    #pragma unroll
    for (int p = 0; p < 4; ++p)
        #pragma unroll
        for (int i = 0; i < 12; ++i) acc[p][i] = 0.f;

    for (int c0 = 0; c0 < CIN; c0 += CHUNK) {
        for (int idx = tid; idx < CHUNK * IH * IW; idx += 256) {
            int ci = idx / (IH * IW);
            int r  = idx % (IH * IW);
            int iy = r / IW, ix = r % IW;
            int gy = tileY + iy - 1, gx = tileX + ix - 1;
            float v = 0.f;
            if ((unsigned)gy < 512u && (unsigned)gx < 512u)
                v = body[(size_t)(c0 + ci) * HWSZ + gy * 512 + gx];
            s_in[ci][iy][ix] = v;
        }
        for (int idx = tid; idx < CHUNK * 9 * COUT; idx += 256) {
            int ci  = idx / (9 * COUT);
            int r   = idx % (9 * COUT);
            int tap = r / COUT, co = r % COUT;
            int hd = co >> 2, cl = co & 3;
            const float* wp = hd == 0 ? w1 : (hd == 1 ? w2 : w3);
            s_w[ci][tap][co] = wp[((size_t)cl * CIN + (c0 + ci)) * 9 + tap];
        }
        __syncthreads();
        #pragma unroll 1
        for (int ci = 0; ci < CHUNK; ++ci) {
            #pragma unroll
            for (int tap = 0; tap < 9; ++tap) {
                const int dy = tap / 3, dx = tap % 3;
                float iv[4];
                #pragma unroll
                for (int p = 0; p < 4; ++p) iv[p] = s_in[ci][ty + dy][tx + dx + p];
                #pragma unroll
                for (int i = 0; i < 12; i += 4) {
                    const float4 wv = *(const float4*)&s_w[ci][tap][i];
                    #pragma unroll
                    for (int p = 0; p < 4; ++p) {
                        acc[p][i + 0] = fmaf(iv[p], wv.x, acc[p][i + 0]);
                        acc[p][i + 1] = fmaf(iv[p], wv.y, acc[p][i + 1]);
                        acc[p][i + 2] = fmaf(iv[p], wv.z, acc[p][i + 2]);
                        acc[p][i + 3] = fmaf(iv[p], wv.w, acc[p][i + 3]);
                    }
                }
            }
        }
        __syncthreads();
    }

    const int gy = tileY + ty, gx = tileX + tx;
    float psum[12];
    #pragma unroll
    for (int co = 0; co < 12; ++co) {
        int hd = co >> 2, cl = co & 3;
        const float* bp = hd == 0 ? b1 : (hd == 1 ? b2 : b3);
        float bs = bp[cl];
        float4 o;
        o.x = acc[0][co] + bs; o.y = acc[1][co] + bs;
        o.z = acc[2][co] + bs; o.w = acc[3][co] + bs;
        psum[co] = o.x + o.y + o.z + o.w;
        *(float4*)&h[(size_t)((hd * 8 + b) * 4 + cl) * HWSZ + gy * 512 + gx] = o;
    }
    // block reduction of GAP partials
    #pragma unroll
    for (int co = 0; co < 12; ++co) {
        #pragma unroll
        for (int off = 32; off >= 1; off >>= 1)
            psum[co] += __shfl_down(psum[co], off);
    }
    const int lane = tid & 63, wv = tid >> 6;
    if (lane == 0) {
        #pragma unroll
        for (int co = 0; co < 12; ++co) s_red[wv][co] = psum[co];
    }
    __syncthreads();
    if (tid < 12) {
        float t = s_red[0][tid] + s_red[1][tid] + s_red[2][tid] + s_red[3][tid];
        atomicAdd(&g[(tid >> 2) * 32 + b * 4 + (tid & 3)], t);
    }
}

// ---------------------------------------------------------------------------
__global__ void zero_k(float* p, int n)
{
    int i = blockIdx.x * 256 + threadIdx.x;
    if (i < n) p[i] = 0.f;
}

// squeeze-excite: s = sigmoid(c2 @ relu(c1 @ mean)) per (head, batch)
__global__ void ca_kernel(const float* __restrict__ g,
                          const float* __restrict__ c11, const float* __restrict__ c12,
                          const float* __restrict__ c21, const float* __restrict__ c22,
                          const float* __restrict__ c31, const float* __restrict__ c32,
                          float* __restrict__ sOut)
{
    int t = threadIdx.x;
    if (t >= 24) return;
    int head = t / 8, b = t % 8;
    const float* c1 = head == 0 ? c11 : (head == 1 ? c21 : c31);
    const float* c2 = head == 0 ? c12 : (head == 1 ? c22 : c32);
    float m[4], v[4];
    #pragma unroll
    for (int i = 0; i < 4; ++i) m[i] = g[head * 32 + b * 4 + i] * (1.0f / 262144.0f);
    #pragma unroll
    for (int j = 0; j < 4; ++j) {
        float x = c1[j*4+0]*m[0] + c1[j*4+1]*m[1] + c1[j*4+2]*m[2] + c1[j*4+3]*m[3];
        v[j] = fmaxf(x, 0.f);
    }
    #pragma unroll
    for (int j = 0; j < 4; ++j) {
        float x = c2[j*4+0]*v[0] + c2[j*4+1]*v[1] + c2[j*4+2]*v[2] + c2[j*4+3]*v[3];
        sOut[head * 32 + b * 4 + j] = 1.f / (1.f + __expf(-x));
    }
}

// ---------------------------------------------------------------------------
// Integral image (SAT): 513x513 per (b,c) plane, zero first row/col.
// ---------------------------------------------------------------------------
__global__ __launch_bounds__(256)
void sat_row(const float* __restrict__ src, float* __restrict__ S)
{
    const int y  = blockIdx.x;     // 0..512
    const int bc = blockIdx.y;     // 0..23
    float* Sp = S + (size_t)bc * 263169;
    const int tid = threadIdx.x;
    if (y == 0) {
        for (int i = tid; i < 513; i += 256) Sp[i] = 0.f;
        return;
    }
    const float2* row2 = (const float2*)(src + (size_t)bc * HWSZ + (size_t)(y - 1) * 512);
    float2 ab = row2[tid];
    float ps = ab.x + ab.y;
    float v = ps;
    const int lane = tid & 63;
    #pragma unroll
    for (int off = 1; off < 64; off <<= 1) {
        float u = __shfl_up(v, off);
        if (lane >= off) v += u;
    }
    __shared__ float wsum[4];
    const int wv = tid >> 6;
    if (lane == 63) wsum[wv] = v;
    __syncthreads();
    float woff = 0.f;
    #pragma unroll
    for (int k = 0; k < 4; ++k) if (k < wv) woff += wsum[k];
    float excl = woff + v - ps;
    float* o = Sp + (size_t)y * 513;
    if (tid == 0) o[0] = 0.f;
    o[1 + 2 * tid] = excl + ab.x;
    o[2 + 2 * tid] = excl + ab.x + ab.y;
}

__global__ __launch_bounds__(512)
void sat_col(float* __restrict__ S)
{
    float* Sp = S + (size_t)blockIdx.x * 263169 + threadIdx.x + 1;
    float run = 0.f;
    for (int i = 1; i <= 512; ++i) {
        float* p = Sp + (size_t)i * 513;
        run += *p;
        *p = run;
    }
}

__device__ __forceinline__ float boxsum(const float* __restrict__ S, int y, int x, int p)
{
    int y0 = max(y - p, 0), x0 = max(x - p, 0);
    int y1 = min(y + p, 511) + 1, x1 = min(x + p, 511) + 1;
    return S[y1 * 513 + x1] - S[y0 * 513 + x1] - S[y1 * 513 + x0] + S[y0 * 513 + x0];
}

// ---------------------------------------------------------------------------
// fuse: softmax(h*s) over 4 channels, then p0*x + p1*blur5 + p2*blur15 + p3*blur25
// ---------------------------------------------------------------------------
__global__ __launch_bounds__(256)
void fuse_kernel(const float* __restrict__ cur, const float* __restrict__ h,
                 const float* __restrict__ sv, const float* __restrict__ S,
                 float* __restrict__ out, int head)
{
    const int idx = blockIdx.x * 256 + threadIdx.x;   // B*H*W
    const int b   = idx >> 18;
    const int rem = idx & 262143;
    const int y   = rem >> 9;
    const int x   = rem & 511;

    const float* sp = sv + head * 32 + b * 4;
    const float* hp = h + (size_t)((head * 8 + b) * 4) * HWSZ + rem;
    float z0 = hp[0]          * sp[0];
    float z1 = hp[HWSZ]       * sp[1];
    float z2 = hp[2 * HWSZ]   * sp[2];
    float z3 = hp[3 * HWSZ]   * sp[3];
    float m  = fmaxf(fmaxf(z0, z1), fmaxf(z2, z3));
    float e0 = __expf(z0 - m), e1 = __expf(z1 - m), e2 = __expf(z2 - m), e3 = __expf(z3 - m);
    float inv = 1.f / (e0 + e1 + e2 + e3);
    float p0 = e0 * inv, p1 = e1 * inv, p2 = e2 * inv, p3 = e3 * inv;

    #pragma unroll
    for (int c = 0; c < 3; ++c) {
        const float* Sp = S + (size_t)(b * 3 + c) * 263169;
        float xv = cur[((size_t)b * 3 + c) * HWSZ + rem];
        float m2 = boxsum(Sp, y, x, 2)  * (1.f / 25.f);
        float m3 = boxsum(Sp, y, x, 7)  * (1.f / 225.f);
        float m4 = boxsum(Sp, y, x, 12) * (1.f / 625.f);
        out[((size_t)b * 3 + c) * HWSZ + rem] = p0 * xv + p1 * m2 + p2 * m3 + p3 * m4;
    }
}

// ---------------------------------------------------------------------------
// Workspace budget (floats):
//   t1   : 32*HW  =  8,388,608   (body1, then body3; later aliased by ping)
//   t2   : 64*HW  = 16,777,216   (body2; later aliased by SAT = 6,316,056)
//   hbuf : 96*HW  = 25,165,824   (3 heads x 8 b x 4 ch raw logits)
//   gbuf/sbuf: 192
// total ~50.3M floats = 201.3 MB  (vs 440 MB in R1, which likely overflowed ws)
// ---------------------------------------------------------------------------
extern "C" void kernel_launch(void* const* d_in, const int* in_sizes, int n_in,
                              void* d_out, int out_size, void* d_ws, size_t ws_size,
                              hipStream_t stream)
{
    (void)in_sizes; (void)n_in; (void)out_size; (void)ws_size;
    const float* x    = (const float*)d_in[0];
    const float* bw1  = (const float*)d_in[1];
    const float* bb1  = (const float*)d_in[2];
    const float* a1   = (const float*)d_in[3];
    const float* bw2  = (const float*)d_in[4];
    const float* bb2  = (const float*)d_in[5];
    const float* a2   = (const float*)d_in[6];
    const float* bw3  = (const float*)d_in[7];
    const float* bb3  = (const float*)d_in[8];
    const float* a3   = (const float*)d_in[9];
    const float* h1w  = (const float*)d_in[10];
    const float* h1b  = (const float*)d_in[11];
    const float* h1c1 = (const float*)d_in[12];
    const float* h1c2 = (const float*)d_in[13];
    const float* h2w  = (const float*)d_in[14];
    const float* h2b  = (const float*)d_in[15];
    const float* h2c1 = (const float*)d_in[16];
    const float* h2c2 = (const float*)d_in[17];
    const float* h3w  = (const float*)d_in[18];
    const float* h3b  = (const float*)d_in[19];
    const float* h3c1 = (const float*)d_in[20];
    const float* h3c2 = (const float*)d_in[21];

    float* ws   = (float*)d_ws;
    float* t1   = ws;                  //  8,388,608 floats
    float* t2   = t1 + 8388608;        // 16,777,216 floats
    float* hbuf = t2 + 16777216;       // 25,165,824 floats
    float* gbuf = hbuf + 25165824;     // 96
    float* sbuf = gbuf + 96;           // 96
    float* SAT  = t2;                  // alias (6,316,056 <= 16,777,216)
    float* ping = t1;                  // alias (6,291,456 <=  8,388,608)

    dim3 blk(256);

    zero_k<<<dim3(1), dim3(128), 0, stream>>>(gbuf, 96);

    // per-batch body pipeline: x[b] -> t1 -> t2 -> t1 -> heads
    for (int b = 0; b < 8; ++b) {
        conv3x3_prelu<3, 32, 3, 32, 16, 16, 4>
            <<<dim3(16, 32, 1), blk, 0, stream>>>(x + (size_t)b * 3 * HWSZ,
                                                  bw1, bb1, a1, t1);
        conv3x3_prelu<32, 64, 8, 32, 8, 16, 4>
            <<<dim3(16, 64, 1), blk, 0, stream>>>(t1, bw2, bb2, a2, t2);
        conv3x3_prelu<64, 32, 8, 32, 16, 16, 4>
            <<<dim3(16, 32, 1), blk, 0, stream>>>(t2, bw3, bb3, a3, t1);
        head_conv<<<dim3(16, 16, 1), blk, 0, stream>>>(t1, h1w, h2w, h3w,
                                                       h1b, h2b, h3b, hbuf, gbuf, b);
    }

    ca_kernel<<<dim3(1), dim3(64), 0, stream>>>(gbuf, h1c1, h1c2, h2c1, h2c2,
                                                h3c1, h3c2, sbuf);

    // fuse chain: x -> ping -> ping(in place) -> d_out
    const float* cur = x;
    for (int i = 0; i < 3; ++i) {
        sat_row<<<dim3(513, 24), blk, 0, stream>>>(cur, SAT);
        sat_col<<<dim3(24), dim3(512), 0, stream>>>(SAT);
        float* nxt = (i == 2) ? (float*)d_out : ping;
        fuse_kernel<<<dim3(8192), blk, 0, stream>>>(cur, hbuf, sbuf, SAT, nxt, i);
        cur = nxt;
    }
}

// Round 3
// 2601.386 us; speedup vs baseline: 1.3276x; 1.3276x over previous
//
#include <hip/hip_runtime.h>
#include <math.h>

#define HWSZ (512*512)

typedef __attribute__((ext_vector_type(8))) short short8;
typedef __attribute__((ext_vector_type(4))) float f32x4;

__device__ __forceinline__ unsigned short f2bf(float f) {
    unsigned u = __float_as_uint(f);
    unsigned r = (u + 0x7FFFu + ((u >> 16) & 1u)) >> 16;
    return (unsigned short)r;
}
__device__ __forceinline__ float bf2f(unsigned short h) {
    return __uint_as_float((unsigned)h << 16);
}

// ---------------------------------------------------------------------------
// Weight prep: OIHW fp32 -> [tap][co][ci] bf16 hi/lo planes (Markidis split)
// conv2: COUT=64,CIN=32 (18432 elems)  conv3: COUT=32,CIN=64 (18432 elems)
// ---------------------------------------------------------------------------
__global__ void prep_weights(const float* __restrict__ w2, const float* __restrict__ w3,
                             unsigned short* __restrict__ w2h, unsigned short* __restrict__ w2l,
                             unsigned short* __restrict__ w3h, unsigned short* __restrict__ w3l)
{
    int i = blockIdx.x * 256 + threadIdx.x;
    if (i >= 36864) return;
    if (i < 18432) {
        int tap = i / 2048, r = i % 2048, co = r / 32, ci = r % 32;
        float v = w2[((co * 32 + ci) * 9) + tap];
        unsigned short h = f2bf(v);
        w2h[i] = h; w2l[i] = f2bf(v - bf2f(h));
    } else {
        int e = i - 18432;
        int tap = e / 2048, r = e % 2048, co = r / 64, ci = r % 64;
        float v = w3[((co * 64 + ci) * 9) + tap];
        unsigned short h = f2bf(v);
        w3h[e] = h; w3l[e] = f2bf(v - bf2f(h));
    }
}

// ---------------------------------------------------------------------------
// 3x3 conv (pad=1) + bias + PReLU via bf16 MFMA 16x16x32, 3-pass compensated.
// Block: 256 thr, output tile = 2 rows x 64 cols x COUT. Shifted-GEMM (9 taps),
// A staged in LDS as [row][col][ci(+pad)] bf16 hi/lo; B-frags from prepped
// global (L2-hot). Wave owns 2 n-tiles so each A-frag feeds 6 MFMAs.
// D layout (verified m89/m91): n=lane&15, m=quad*4+reg. A: m=lane&15,k=quad*8+j.
// ---------------------------------------------------------------------------
template<int CIN, int COUT>
__global__ __launch_bounds__(256, 3)
void conv3x3_mfma(const float* __restrict__ in,
                  const unsigned short* __restrict__ wh,
                  const unsigned short* __restrict__ wl,
                  const float* __restrict__ bias,
                  const float* __restrict__ alpha,
                  float* __restrict__ out)
{
    constexpr int NT2   = COUT / 32;        // wave-groups in n (2 or 1)
    constexpr int MTW   = 2 * NT2;          // m-tiles per wave (4 or 2)
    constexpr int CIP   = 40;               // 32 ci + 8 pad (keeps 16B align)
    constexpr int PLANE = 4 * 68 * CIP;     // 10880 elems per hi/lo plane

    __shared__ __align__(16) unsigned short s_a[2 * PLANE];  // 43,520 B

    const int tid  = threadIdx.x;
    const int w    = tid >> 6;
    const int lane = tid & 63;
    const int ln   = lane & 15;
    const int quad = lane >> 4;
    const int ng   = w % NT2;
    const int mg   = w / NT2;
    const int x1   = blockIdx.x * 64;
    const int y0   = blockIdx.y * 2;
    const int cobase = ng * 32;

    f32x4 acc[MTW][2];
    #pragma unroll
    for (int mt = 0; mt < MTW; ++mt)
        #pragma unroll
        for (int nt = 0; nt < 2; ++nt)
            acc[mt][nt] = (f32x4){0.f, 0.f, 0.f, 0.f};

    for (int c0 = 0; c0 < CIN; c0 += 32) {
        if (c0) __syncthreads();
        // ---- stage 4 rows x 66 cols x 32 ci, split into bf16 hi/lo planes ----
        for (int idx = tid; idx < 32 * 4 * 66; idx += 256) {
            int ci = idx / 264;
            int rm = idx % 264;
            int r  = rm / 66, xx = rm % 66;
            int gy = y0 - 1 + r, gx = x1 - 1 + xx;
            float v = 0.f;
            if ((unsigned)gy < 512u && (unsigned)gx < 512u)
                v = in[(size_t)(c0 + ci) * HWSZ + gy * 512 + gx];
            unsigned short h = f2bf(v);
            unsigned short l = f2bf(v - bf2f(h));
            int base = (r * 68 + xx) * CIP + ci;
            s_a[base] = h;
            s_a[PLANE + base] = l;
        }
        __syncthreads();

        #pragma unroll
        for (int tap = 0; tap < 9; ++tap) {
            const int dy = tap / 3, dx = tap % 3;
            const unsigned short* bp  = wh + ((size_t)(tap * COUT + cobase + ln) * CIN + c0 + quad * 8);
            const unsigned short* bpl = wl + ((size_t)(tap * COUT + cobase + ln) * CIN + c0 + quad * 8);
            short8 bh0 = *(const short8*)bp;
            short8 bh1 = *(const short8*)(bp + 16 * CIN);
            short8 bl0 = *(const short8*)bpl;
            short8 bl1 = *(const short8*)(bpl + 16 * CIN);
            #pragma unroll
            for (int mt = 0; mt < MTW; ++mt) {
                const int mti = mg * MTW + mt;
                const int rr  = (mti >> 2) + dy;
                const int col = ((mti & 3) << 4) + ln + dx;
                const int off = (rr * 68 + col) * CIP + quad * 8;
                short8 ah = *(const short8*)&s_a[off];
                short8 al = *(const short8*)&s_a[PLANE + off];
                acc[mt][0] = __builtin_amdgcn_mfma_f32_16x16x32_bf16(ah, bh0, acc[mt][0], 0, 0, 0);
                acc[mt][0] = __builtin_amdgcn_mfma_f32_16x16x32_bf16(al, bh0, acc[mt][0], 0, 0, 0);
                acc[mt][0] = __builtin_amdgcn_mfma_f32_16x16x32_bf16(ah, bl0, acc[mt][0], 0, 0, 0);
                acc[mt][1] = __builtin_amdgcn_mfma_f32_16x16x32_bf16(ah, bh1, acc[mt][1], 0, 0, 0);
                acc[mt][1] = __builtin_amdgcn_mfma_f32_16x16x32_bf16(al, bh1, acc[mt][1], 0, 0, 0);
                acc[mt][1] = __builtin_amdgcn_mfma_f32_16x16x32_bf16(ah, bl1, acc[mt][1], 0, 0, 0);
            }
        }
    }

    // ---- epilogue: bias + PReLU + float4 stores ----
    const float av = alpha[0];
    #pragma unroll
    for (int nt = 0; nt < 2; ++nt) {
        const int co = cobase + nt * 16 + ln;
        const float bs = bias[co];
        #pragma unroll
        for (int mt = 0; mt < MTW; ++mt) {
            const int mti = mg * MTW + mt;
            const int y = y0 + (mti >> 2);
            const int x = x1 + ((mti & 3) << 4) + quad * 4;
            float4 o; float t;
            t = acc[mt][nt][0] + bs; o.x = t > 0.f ? t : av * t;
            t = acc[mt][nt][1] + bs; o.y = t > 0.f ? t : av * t;
            t = acc[mt][nt][2] + bs; o.z = t > 0.f ? t : av * t;
            t = acc[mt][nt][3] + bs; o.w = t > 0.f ? t : av * t;
            *(float4*)&out[(size_t)co * HWSZ + y * 512 + x] = o;
        }
    }
}

// ---------------------------------------------------------------------------
// Direct fp32 3x3 conv + bias + PReLU (kept for conv1: 3->32).
// ---------------------------------------------------------------------------
template<int CIN, int COUT, int CHUNK, int TW, int TH, int CO_T, int PX_T>
__global__ __launch_bounds__(256)
void conv3x3_prelu(const float* __restrict__ in, const float* __restrict__ wgt,
                   const float* __restrict__ bias, const float* __restrict__ alpha,
                   float* __restrict__ out)
{
    constexpr int CG  = COUT / CO_T;
    constexpr int PG  = 256 / CG;
    static_assert(PG * PX_T == TW * TH, "tile mismatch");
    constexpr int IW  = TW + 2;
    constexpr int IWP = TW + 3;
    constexpr int IH  = TH + 2;

    __shared__ __align__(16) float s_in[CHUNK][IH][IWP];
    __shared__ __align__(16) float s_w[CHUNK][9][COUT];

    const int tid = threadIdx.x;
    const int cg  = tid / PG;
    const int pg  = tid % PG;
    const int pl  = pg * PX_T;
    const int ty  = pl / TW;
    const int tx  = pl % TW;
    const int tileX = blockIdx.x * TW;
    const int tileY = blockIdx.y * TH;

    float acc[PX_T][CO_T];
    #pragma unroll
    for (int p = 0; p < PX_T; ++p)
        #pragma unroll
        for (int i = 0; i < CO_T; ++i) acc[p][i] = 0.f;

    for (int c0 = 0; c0 < CIN; c0 += CHUNK) {
        for (int idx = tid; idx < CHUNK * IH * IW; idx += 256) {
            int ci = idx / (IH * IW);
            int r  = idx % (IH * IW);
            int iy = r / IW, ix = r % IW;
            int gy = tileY + iy - 1, gx = tileX + ix - 1;
            float v = 0.f;
            if ((unsigned)gy < 512u && (unsigned)gx < 512u)
                v = in[(size_t)(c0 + ci) * HWSZ + gy * 512 + gx];
            s_in[ci][iy][ix] = v;
        }
        for (int idx = tid; idx < CHUNK * 9 * COUT; idx += 256) {
            int ci  = idx / (9 * COUT);
            int r   = idx % (9 * COUT);
            int tap = r / COUT, co = r % COUT;
            s_w[ci][tap][co] = wgt[((size_t)co * CIN + (c0 + ci)) * 9 + tap];
        }
        __syncthreads();

        #pragma unroll 1
        for (int ci = 0; ci < CHUNK; ++ci) {
            #pragma unroll
            for (int tap = 0; tap < 9; ++tap) {
                const int dy = tap / 3, dx = tap % 3;
                float iv[PX_T];
                #pragma unroll
                for (int p = 0; p < PX_T; ++p) iv[p] = s_in[ci][ty + dy][tx + dx + p];
                #pragma unroll
                for (int i = 0; i < CO_T; i += 4) {
                    const float4 wv = *(const float4*)&s_w[ci][tap][cg * CO_T + i];
                    #pragma unroll
                    for (int p = 0; p < PX_T; ++p) {
                        acc[p][i + 0] = fmaf(iv[p], wv.x, acc[p][i + 0]);
                        acc[p][i + 1] = fmaf(iv[p], wv.y, acc[p][i + 1]);
                        acc[p][i + 2] = fmaf(iv[p], wv.z, acc[p][i + 2]);
                        acc[p][i + 3] = fmaf(iv[p], wv.w, acc[p][i + 3]);
                    }
                }
            }
        }
        __syncthreads();
    }

    const float a  = alpha[0];
    const int  gy  = tileY + ty;
    const int  gx  = tileX + tx;
    #pragma unroll
    for (int i = 0; i < CO_T; ++i) {
        const int co = cg * CO_T + i;
        const float bs = bias[co];
        float4 o;
        float t;
        t = acc[0][i] + bs; o.x = t > 0.f ? t : a * t;
        t = acc[1][i] + bs; o.y = t > 0.f ? t : a * t;
        t = acc[2][i] + bs; o.z = t > 0.f ? t : a * t;
        t = acc[3][i] + bs; o.w = t > 0.f ? t : a * t;
        *(float4*)&out[((size_t)co) * HWSZ + gy * 512 + gx] = o;
    }
}

// ---------------------------------------------------------------------------
// Fused 3-head conv 32->4 (+bias) with GAP partial reduction (atomicAdd).
// ---------------------------------------------------------------------------
__global__ __launch_bounds__(256)
void head_conv(const float* __restrict__ body,
               const float* __restrict__ w1, const float* __restrict__ w2,
               const float* __restrict__ w3,
               const float* __restrict__ b1, const float* __restrict__ b2,
               const float* __restrict__ b3,
               float* __restrict__ h, float* __restrict__ g, int b)
{
    constexpr int TW = 32, TH = 32, CHUNK = 8, CIN = 32, COUT = 12;
    constexpr int IW = TW + 2, IWP = TW + 3, IH = TH + 2;
    __shared__ __align__(16) float s_in[CHUNK][IH][IWP];
    __shared__ __align__(16) float s_w[CHUNK][9][COUT];
    __shared__ float s_red[4][12];

    const int tid = threadIdx.x;
    const int ty  = tid >> 3;
    const int tx  = (tid & 7) << 2;
    const int tileX = blockIdx.x * TW;
    const int tileY = blockIdx.y * TH;

    float acc[4][12];
    #pragma unroll
    for (int p = 0; p < 4; ++p)
        #pragma unroll
        for (int i = 0; i < 12; ++i) acc[p][i] = 0.f;

    for (int c0 = 0; c0 < CIN; c0 += CHUNK) {
        for (int idx = tid; idx < CHUNK * IH * IW; idx += 256) {
            int ci = idx / (IH * IW);
            int r  = idx % (IH * IW);
            int iy = r / IW, ix = r % IW;
            int gy = tileY + iy - 1, gx = tileX + ix - 1;
            float v = 0.f;
            if ((unsigned)gy < 512u && (unsigned)gx < 512u)
                v = body[(size_t)(c0 + ci) * HWSZ + gy * 512 + gx];
            s_in[ci][iy][ix] = v;
        }
        for (int idx = tid; idx < CHUNK * 9 * COUT; idx += 256) {
            int ci  = idx / (9 * COUT);
            int r   = idx % (9 * COUT);
            int tap = r / COUT, co = r % COUT;
            int hd = co >> 2, cl = co & 3;
            const float* wp = hd == 0 ? w1 : (hd == 1 ? w2 : w3);
            s_w[ci][tap][co] = wp[((size_t)cl * CIN + (c0 + ci)) * 9 + tap];
        }
        __syncthreads();
        #pragma unroll 1
        for (int ci = 0; ci < CHUNK; ++ci) {
            #pragma unroll
            for (int tap = 0; tap < 9; ++tap) {
                const int dy = tap / 3, dx = tap % 3;
                float iv[4];
                #pragma unroll
                for (int p = 0; p < 4; ++p) iv[p] = s_in[ci][ty + dy][tx + dx + p];
                #pragma unroll
                for (int i = 0; i < 12; i += 4) {
                    const float4 wv = *(const float4*)&s_w[ci][tap][i];
                    #pragma unroll
                    for (int p = 0; p < 4; ++p) {
                        acc[p][i + 0] = fmaf(iv[p], wv.x, acc[p][i + 0]);
                        acc[p][i + 1] = fmaf(iv[p], wv.y, acc[p][i + 1]);
                        acc[p][i + 2] = fmaf(iv[p], wv.z, acc[p][i + 2]);
                        acc[p][i + 3] = fmaf(iv[p], wv.w, acc[p][i + 3]);
                    }
                }
            }
        }
        __syncthreads();
    }

    const int gy = tileY + ty, gx = tileX + tx;
    float psum[12];
    #pragma unroll
    for (int co = 0; co < 12; ++co) {
        int hd = co >> 2, cl = co & 3;
        const float* bp = hd == 0 ? b1 : (hd == 1 ? b2 : b3);
        float bs = bp[cl];
        float4 o;
        o.x = acc[0][co] + bs; o.y = acc[1][co] + bs;
        o.z = acc[2][co] + bs; o.w = acc[3][co] + bs;
        psum[co] = o.x + o.y + o.z + o.w;
        *(float4*)&h[(size_t)((hd * 8 + b) * 4 + cl) * HWSZ + gy * 512 + gx] = o;
    }
    #pragma unroll
    for (int co = 0; co < 12; ++co) {
        #pragma unroll
        for (int off = 32; off >= 1; off >>= 1)
            psum[co] += __shfl_down(psum[co], off);
    }
    const int lane = tid & 63, wv = tid >> 6;
    if (lane == 0) {
        #pragma unroll
        for (int co = 0; co < 12; ++co) s_red[wv][co] = psum[co];
    }
    __syncthreads();
    if (tid < 12) {
        float t = s_red[0][tid] + s_red[1][tid] + s_red[2][tid] + s_red[3][tid];
        atomicAdd(&g[(tid >> 2) * 32 + b * 4 + (tid & 3)], t);
    }
}

// ---------------------------------------------------------------------------
__global__ void zero_k(float* p, int n)
{
    int i = blockIdx.x * 256 + threadIdx.x;
    if (i < n) p[i] = 0.f;
}

__global__ void ca_kernel(const float* __restrict__ g,
                          const float* __restrict__ c11, const float* __restrict__ c12,
                          const float* __restrict__ c21, const float* __restrict__ c22,
                          const float* __restrict__ c31, const float* __restrict__ c32,
                          float* __restrict__ sOut)
{
    int t = threadIdx.x;
    if (t >= 24) return;
    int head = t / 8, b = t % 8;
    const float* c1 = head == 0 ? c11 : (head == 1 ? c21 : c31);
    const float* c2 = head == 0 ? c12 : (head == 1 ? c22 : c32);
    float m[4], v[4];
    #pragma unroll
    for (int i = 0; i < 4; ++i) m[i] = g[head * 32 + b * 4 + i] * (1.0f / 262144.0f);
    #pragma unroll
    for (int j = 0; j < 4; ++j) {
        float x = c1[j*4+0]*m[0] + c1[j*4+1]*m[1] + c1[j*4+2]*m[2] + c1[j*4+3]*m[3];
        v[j] = fmaxf(x, 0.f);
    }
    #pragma unroll
    for (int j = 0; j < 4; ++j) {
        float x = c2[j*4+0]*v[0] + c2[j*4+1]*v[1] + c2[j*4+2]*v[2] + c2[j*4+3]*v[3];
        sOut[head * 32 + b * 4 + j] = 1.f / (1.f + __expf(-x));
    }
}

// ---------------------------------------------------------------------------
__global__ __launch_bounds__(256)
void sat_row(const float* __restrict__ src, float* __restrict__ S)
{
    const int y  = blockIdx.x;
    const int bc = blockIdx.y;
    float* Sp = S + (size_t)bc * 263169;
    const int tid = threadIdx.x;
    if (y == 0) {
        for (int i = tid; i < 513; i += 256) Sp[i] = 0.f;
        return;
    }
    const float2* row2 = (const float2*)(src + (size_t)bc * HWSZ + (size_t)(y - 1) * 512);
    float2 ab = row2[tid];
    float ps = ab.x + ab.y;
    float v = ps;
    const int lane = tid & 63;
    #pragma unroll
    for (int off = 1; off < 64; off <<= 1) {
        float u = __shfl_up(v, off);
        if (lane >= off) v += u;
    }
    __shared__ float wsum[4];
    const int wv = tid >> 6;
    if (lane == 63) wsum[wv] = v;
    __syncthreads();
    float woff = 0.f;
    #pragma unroll
    for (int k = 0; k < 4; ++k) if (k < wv) woff += wsum[k];
    float excl = woff + v - ps;
    float* o = Sp + (size_t)y * 513;
    if (tid == 0) o[0] = 0.f;
    o[1 + 2 * tid] = excl + ab.x;
    o[2 + 2 * tid] = excl + ab.x + ab.y;
}

__global__ __launch_bounds__(512)
void sat_col(float* __restrict__ S)
{
    float* Sp = S + (size_t)blockIdx.x * 263169 + threadIdx.x + 1;
    float run = 0.f;
    for (int i = 1; i <= 512; ++i) {
        float* p = Sp + (size_t)i * 513;
        run += *p;
        *p = run;
    }
}

__device__ __forceinline__ float boxsum(const float* __restrict__ S, int y, int x, int p)
{
    int y0 = max(y - p, 0), x0 = max(x - p, 0);
    int y1 = min(y + p, 511) + 1, x1 = min(x + p, 511) + 1;
    return S[y1 * 513 + x1] - S[y0 * 513 + x1] - S[y1 * 513 + x0] + S[y0 * 513 + x0];
}

__global__ __launch_bounds__(256)
void fuse_kernel(const float* __restrict__ cur, const float* __restrict__ h,
                 const float* __restrict__ sv, const float* __restrict__ S,
                 float* __restrict__ out, int head)
{
    const int idx = blockIdx.x * 256 + threadIdx.x;
    const int b   = idx >> 18;
    const int rem = idx & 262143;
    const int y   = rem >> 9;
    const int x   = rem & 511;

    const float* sp = sv + head * 32 + b * 4;
    const float* hp = h + (size_t)((head * 8 + b) * 4) * HWSZ + rem;
    float z0 = hp[0]          * sp[0];
    float z1 = hp[HWSZ]       * sp[1];
    float z2 = hp[2 * HWSZ]   * sp[2];
    float z3 = hp[3 * HWSZ]   * sp[3];
    float m  = fmaxf(fmaxf(z0, z1), fmaxf(z2, z3));
    float e0 = __expf(z0 - m), e1 = __expf(z1 - m), e2 = __expf(z2 - m), e3 = __expf(z3 - m);
    float inv = 1.f / (e0 + e1 + e2 + e3);
    float p0 = e0 * inv, p1 = e1 * inv, p2 = e2 * inv, p3 = e3 * inv;

    #pragma unroll
    for (int c = 0; c < 3; ++c) {
        const float* Sp = S + (size_t)(b * 3 + c) * 263169;
        float xv = cur[((size_t)b * 3 + c) * HWSZ + rem];
        float m2 = boxsum(Sp, y, x, 2)  * (1.f / 25.f);
        float m3 = boxsum(Sp, y, x, 7)  * (1.f / 225.f);
        float m4 = boxsum(Sp, y, x, 12) * (1.f / 625.f);
        out[((size_t)b * 3 + c) * HWSZ + rem] = p0 * xv + p1 * m2 + p2 * m3 + p3 * m4;
    }
}

// ---------------------------------------------------------------------------
// Workspace (floats): t1 8,388,608 | t2 16,777,216 | hbuf 25,165,824
// | gbuf 96 | sbuf 96 | packed bf16 weights 55,296  ->  ~201.5 MB total
// ---------------------------------------------------------------------------
extern "C" void kernel_launch(void* const* d_in, const int* in_sizes, int n_in,
                              void* d_out, int out_size, void* d_ws, size_t ws_size,
                              hipStream_t stream)
{
    (void)in_sizes; (void)n_in; (void)out_size; (void)ws_size;
    const float* x    = (const float*)d_in[0];
    const float* bw1  = (const float*)d_in[1];
    const float* bb1  = (const float*)d_in[2];
    const float* a1   = (const float*)d_in[3];
    const float* bw2  = (const float*)d_in[4];
    const float* bb2  = (const float*)d_in[5];
    const float* a2   = (const float*)d_in[6];
    const float* bw3  = (const float*)d_in[7];
    const float* bb3  = (const float*)d_in[8];
    const float* a3   = (const float*)d_in[9];
    const float* h1w  = (const float*)d_in[10];
    const float* h1b  = (const float*)d_in[11];
    const float* h1c1 = (const float*)d_in[12];
    const float* h1c2 = (const float*)d_in[13];
    const float* h2w  = (const float*)d_in[14];
    const float* h2b  = (const float*)d_in[15];
    const float* h2c1 = (const float*)d_in[16];
    const float* h2c2 = (const float*)d_in[17];
    const float* h3w  = (const float*)d_in[18];
    const float* h3b  = (const float*)d_in[19];
    const float* h3c1 = (const float*)d_in[20];
    const float* h3c2 = (const float*)d_in[21];

    float* ws   = (float*)d_ws;
    float* t1   = ws;
    float* t2   = t1 + 8388608;
    float* hbuf = t2 + 16777216;
    float* gbuf = hbuf + 25165824;
    float* sbuf = gbuf + 96;
    unsigned short* w2h = (unsigned short*)(sbuf + 96);
    unsigned short* w2l = w2h + 18432;
    unsigned short* w3h = w2l + 18432;
    unsigned short* w3l = w3h + 18432;
    float* SAT  = t2;                  // alias (6,316,056 <= 16,777,216)
    float* ping = t1;                  // alias (6,291,456 <=  8,388,608)

    dim3 blk(256);

    prep_weights<<<dim3(144), blk, 0, stream>>>(bw2, bw3, w2h, w2l, w3h, w3l);
    zero_k<<<dim3(1), dim3(128), 0, stream>>>(gbuf, 96);

    // per-batch body pipeline: x[b] -> t1 -> t2 -> t1 -> heads
    for (int b = 0; b < 8; ++b) {
        conv3x3_prelu<3, 32, 3, 32, 16, 16, 4>
            <<<dim3(16, 32, 1), blk, 0, stream>>>(x + (size_t)b * 3 * HWSZ,
                                                  bw1, bb1, a1, t1);
        conv3x3_mfma<32, 64>
            <<<dim3(8, 256), blk, 0, stream>>>(t1, w2h, w2l, bb2, a2, t2);
        conv3x3_mfma<64, 32>
            <<<dim3(8, 256), blk, 0, stream>>>(t2, w3h, w3l, bb3, a3, t1);
        head_conv<<<dim3(16, 16, 1), blk, 0, stream>>>(t1, h1w, h2w, h3w,
                                                       h1b, h2b, h3b, hbuf, gbuf, b);
    }

    ca_kernel<<<dim3(1), dim3(64), 0, stream>>>(gbuf, h1c1, h1c2, h2c1, h2c2,
                                                h3c1, h3c2, sbuf);

    // fuse chain: x -> ping -> ping(in place) -> d_out
    const float* cur = x;
    for (int i = 0; i < 3; ++i) {
        sat_row<<<dim3(513, 24), blk, 0, stream>>>(cur, SAT);
        sat_col<<<dim3(24), dim3(512), 0, stream>>>(SAT);
        float* nxt = (i == 2) ? (float*)d_out : ping;
        fuse_kernel<<<dim3(8192), blk, 0, stream>>>(cur, hbuf, sbuf, SAT, nxt, i);
        cur = nxt;
    }
}

// Round 4
// 2468.559 us; speedup vs baseline: 1.3990x; 1.0538x over previous
//
#include <hip/hip_runtime.h>
#include <math.h>

#define HWSZ (512*512)

typedef __attribute__((ext_vector_type(8))) short short8;
typedef __attribute__((ext_vector_type(4))) float f32x4;

__device__ __forceinline__ unsigned short f2bf(float f) {
    unsigned u = __float_as_uint(f);
    unsigned r = (u + 0x7FFFu + ((u >> 16) & 1u)) >> 16;
    return (unsigned short)r;
}
__device__ __forceinline__ float bf2f(unsigned short h) {
    return __uint_as_float((unsigned)h << 16);
}

// ---------------------------------------------------------------------------
// Weight prep: OIHW fp32 -> [tap][co][ci] bf16 hi/lo planes (Markidis split)
// ---------------------------------------------------------------------------
__global__ void prep_weights(const float* __restrict__ w2, const float* __restrict__ w3,
                             unsigned short* __restrict__ w2h, unsigned short* __restrict__ w2l,
                             unsigned short* __restrict__ w3h, unsigned short* __restrict__ w3l)
{
    int i = blockIdx.x * 256 + threadIdx.x;
    if (i >= 36864) return;
    if (i < 18432) {
        int tap = i / 2048, r = i % 2048, co = r / 32, ci = r % 32;
        float v = w2[((co * 32 + ci) * 9) + tap];
        unsigned short h = f2bf(v);
        w2h[i] = h; w2l[i] = f2bf(v - bf2f(h));
    } else {
        int e = i - 18432;
        int tap = e / 2048, r = e % 2048, co = r / 64, ci = r % 64;
        float v = w3[((co * 64 + ci) * 9) + tap];
        unsigned short h = f2bf(v);
        w3h[e] = h; w3l[e] = f2bf(v - bf2f(h));
    }
}

// ---------------------------------------------------------------------------
// 3x3 conv (pad=1) + bias + PReLU via bf16 MFMA 16x16x32, 3-pass compensated.
// R4: granule-major LDS (conflict-free b128 reads + free staging writes),
// pass-major MFMA order (dep distance 8/4), 37 KB LDS -> 4 blocks/CU.
// LDS addr(plane p, ci, row r, col c) = p*9248 + (ci/8)*2312 + (r*72+c)*8 + ci%8
//   granule stride 2312 shorts = 4624 B == 4 banks (mod 32)  -> minimal reads
// ---------------------------------------------------------------------------
template<int CIN, int COUT>
__global__ __launch_bounds__(256, 4)
void conv3x3_mfma(const float* __restrict__ in,
                  const unsigned short* __restrict__ wh,
                  const unsigned short* __restrict__ wl,
                  const float* __restrict__ bias,
                  const float* __restrict__ alpha,
                  float* __restrict__ out)
{
    constexpr int NT2   = COUT / 32;        // wave-groups in n (2 or 1)
    constexpr int MTW   = 2 * NT2;          // m-tiles per wave (4 or 2)
    constexpr int GRAN  = 2312;             // granule stride (shorts)
    constexpr int PLANE = 4 * GRAN;         // 9248 shorts per hi/lo plane

    __shared__ __align__(16) unsigned short s_a[2 * PLANE];  // 36,992 B

    const int tid  = threadIdx.x;
    const int w    = tid >> 6;
    const int lane = tid & 63;
    const int ln   = lane & 15;
    const int quad = lane >> 4;
    const int ng   = w % NT2;
    const int mg   = w / NT2;
    const int x1   = blockIdx.x * 64;
    const int y0   = blockIdx.y * 2;
    const int cobase = ng * 32;

    // staging lane split: 8 cols x 8 ci per wave-iteration
    const int dxs = lane >> 3;   // 0..7 col within block
    const int cis = lane & 7;    // 0..7 ci within granule

    f32x4 acc[MTW][2];
    #pragma unroll
    for (int mt = 0; mt < MTW; ++mt)
        #pragma unroll
        for (int nt = 0; nt < 2; ++nt)
            acc[mt][nt] = (f32x4){0.f, 0.f, 0.f, 0.f};

    for (int c0 = 0; c0 < CIN; c0 += 32) {
        if (c0) __syncthreads();
        // ---- stage 4 rows x 72 cols x 32 ci, bf16 hi/lo split ----
        // per wave-iter: granule g, row r, col-block cb; lanes: 8 cols x 8 ci.
        // LDS writes land on 64 consecutive shorts -> conflict-free.
        for (int it = w; it < 144; it += 4) {
            int g  = it / 36;
            int rm = it % 36;
            int r  = rm / 9;
            int cb = rm % 9;
            int col = cb * 8 + dxs;          // 0..71
            int ci  = g * 8 + cis;           // 0..31
            int gy = y0 - 1 + r;
            int gx = x1 - 1 + col;
            float v = 0.f;
            if ((unsigned)gy < 512u && (unsigned)gx < 512u)
                v = in[(size_t)(c0 + ci) * HWSZ + gy * 512 + gx];
            unsigned short h = f2bf(v);
            unsigned short l = f2bf(v - bf2f(h));
            int sa = g * GRAN + (r * 72 + col) * 8 + cis;
            s_a[sa] = h;
            s_a[PLANE + sa] = l;
        }
        __syncthreads();

        #pragma unroll
        for (int tap = 0; tap < 9; ++tap) {
            const int dy = tap / 3, dx = tap % 3;
            const unsigned short* bp  = wh + ((size_t)(tap * COUT + cobase + ln) * CIN + c0 + quad * 8);
            const unsigned short* bpl = wl + ((size_t)(tap * COUT + cobase + ln) * CIN + c0 + quad * 8);
            short8 bh0 = *(const short8*)bp;
            short8 bh1 = *(const short8*)(bp + 16 * CIN);
            short8 bl0 = *(const short8*)bpl;
            short8 bl1 = *(const short8*)(bpl + 16 * CIN);

            short8 ah[MTW], al[MTW];
            #pragma unroll
            for (int mt = 0; mt < MTW; ++mt) {
                const int mti = mg * MTW + mt;
                const int rr  = (mti >> 2) + dy;
                const int col = ((mti & 3) << 4) + ln + dx;
                const int off = quad * GRAN + (rr * 72 + col) * 8;
                ah[mt] = *(const short8*)&s_a[off];
                al[mt] = *(const short8*)&s_a[PLANE + off];
            }
            // pass-major: dependent MFMAs on the same acc are 2*MTW apart
            #pragma unroll
            for (int mt = 0; mt < MTW; ++mt)
                acc[mt][0] = __builtin_amdgcn_mfma_f32_16x16x32_bf16(ah[mt], bh0, acc[mt][0], 0, 0, 0);
            #pragma unroll
            for (int mt = 0; mt < MTW; ++mt)
                acc[mt][1] = __builtin_amdgcn_mfma_f32_16x16x32_bf16(ah[mt], bh1, acc[mt][1], 0, 0, 0);
            #pragma unroll
            for (int mt = 0; mt < MTW; ++mt)
                acc[mt][0] = __builtin_amdgcn_mfma_f32_16x16x32_bf16(al[mt], bh0, acc[mt][0], 0, 0, 0);
            #pragma unroll
            for (int mt = 0; mt < MTW; ++mt)
                acc[mt][1] = __builtin_amdgcn_mfma_f32_16x16x32_bf16(al[mt], bh1, acc[mt][1], 0, 0, 0);
            #pragma unroll
            for (int mt = 0; mt < MTW; ++mt)
                acc[mt][0] = __builtin_amdgcn_mfma_f32_16x16x32_bf16(ah[mt], bl0, acc[mt][0], 0, 0, 0);
            #pragma unroll
            for (int mt = 0; mt < MTW; ++mt)
                acc[mt][1] = __builtin_amdgcn_mfma_f32_16x16x32_bf16(ah[mt], bl1, acc[mt][1], 0, 0, 0);
        }
    }

    // ---- epilogue: bias + PReLU + float4 stores ----
    const float av = alpha[0];
    #pragma unroll
    for (int nt = 0; nt < 2; ++nt) {
        const int co = cobase + nt * 16 + ln;
        const float bs = bias[co];
        #pragma unroll
        for (int mt = 0; mt < MTW; ++mt) {
            const int mti = mg * MTW + mt;
            const int y = y0 + (mti >> 2);
            const int x = x1 + ((mti & 3) << 4) + quad * 4;
            float4 o; float t;
            t = acc[mt][nt][0] + bs; o.x = t > 0.f ? t : av * t;
            t = acc[mt][nt][1] + bs; o.y = t > 0.f ? t : av * t;
            t = acc[mt][nt][2] + bs; o.z = t > 0.f ? t : av * t;
            t = acc[mt][nt][3] + bs; o.w = t > 0.f ? t : av * t;
            *(float4*)&out[(size_t)co * HWSZ + y * 512 + x] = o;
        }
    }
}

// ---------------------------------------------------------------------------
// Direct fp32 3x3 conv + bias + PReLU (kept for conv1: 3->32).
// ---------------------------------------------------------------------------
template<int CIN, int COUT, int CHUNK, int TW, int TH, int CO_T, int PX_T>
__global__ __launch_bounds__(256)
void conv3x3_prelu(const float* __restrict__ in, const float* __restrict__ wgt,
                   const float* __restrict__ bias, const float* __restrict__ alpha,
                   float* __restrict__ out)
{
    constexpr int CG  = COUT / CO_T;
    constexpr int PG  = 256 / CG;
    static_assert(PG * PX_T == TW * TH, "tile mismatch");
    constexpr int IW  = TW + 2;
    constexpr int IWP = TW + 3;
    constexpr int IH  = TH + 2;

    __shared__ __align__(16) float s_in[CHUNK][IH][IWP];
    __shared__ __align__(16) float s_w[CHUNK][9][COUT];

    const int tid = threadIdx.x;
    const int cg  = tid / PG;
    const int pg  = tid % PG;
    const int pl  = pg * PX_T;
    const int ty  = pl / TW;
    const int tx  = pl % TW;
    const int tileX = blockIdx.x * TW;
    const int tileY = blockIdx.y * TH;

    float acc[PX_T][CO_T];
    #pragma unroll
    for (int p = 0; p < PX_T; ++p)
        #pragma unroll
        for (int i = 0; i < CO_T; ++i) acc[p][i] = 0.f;

    for (int c0 = 0; c0 < CIN; c0 += CHUNK) {
        for (int idx = tid; idx < CHUNK * IH * IW; idx += 256) {
            int ci = idx / (IH * IW);
            int r  = idx % (IH * IW);
            int iy = r / IW, ix = r % IW;
            int gy = tileY + iy - 1, gx = tileX + ix - 1;
            float v = 0.f;
            if ((unsigned)gy < 512u && (unsigned)gx < 512u)
                v = in[(size_t)(c0 + ci) * HWSZ + gy * 512 + gx];
            s_in[ci][iy][ix] = v;
        }
        for (int idx = tid; idx < CHUNK * 9 * COUT; idx += 256) {
            int ci  = idx / (9 * COUT);
            int r   = idx % (9 * COUT);
            int tap = r / COUT, co = r % COUT;
            s_w[ci][tap][co] = wgt[((size_t)co * CIN + (c0 + ci)) * 9 + tap];
        }
        __syncthreads();

        #pragma unroll 1
        for (int ci = 0; ci < CHUNK; ++ci) {
            #pragma unroll
            for (int tap = 0; tap < 9; ++tap) {
                const int dy = tap / 3, dx = tap % 3;
                float iv[PX_T];
                #pragma unroll
                for (int p = 0; p < PX_T; ++p) iv[p] = s_in[ci][ty + dy][tx + dx + p];
                #pragma unroll
                for (int i = 0; i < CO_T; i += 4) {
                    const float4 wv = *(const float4*)&s_w[ci][tap][cg * CO_T + i];
                    #pragma unroll
                    for (int p = 0; p < PX_T; ++p) {
                        acc[p][i + 0] = fmaf(iv[p], wv.x, acc[p][i + 0]);
                        acc[p][i + 1] = fmaf(iv[p], wv.y, acc[p][i + 1]);
                        acc[p][i + 2] = fmaf(iv[p], wv.z, acc[p][i + 2]);
                        acc[p][i + 3] = fmaf(iv[p], wv.w, acc[p][i + 3]);
                    }
                }
            }
        }
        __syncthreads();
    }

    const float a  = alpha[0];
    const int  gy  = tileY + ty;
    const int  gx  = tileX + tx;
    #pragma unroll
    for (int i = 0; i < CO_T; ++i) {
        const int co = cg * CO_T + i;
        const float bs = bias[co];
        float4 o;
        float t;
        t = acc[0][i] + bs; o.x = t > 0.f ? t : a * t;
        t = acc[1][i] + bs; o.y = t > 0.f ? t : a * t;
        t = acc[2][i] + bs; o.z = t > 0.f ? t : a * t;
        t = acc[3][i] + bs; o.w = t > 0.f ? t : a * t;
        *(float4*)&out[((size_t)co) * HWSZ + gy * 512 + gx] = o;
    }
}

// ---------------------------------------------------------------------------
// Fused 3-head conv 32->4 (+bias) with GAP partial reduction (atomicAdd).
// ---------------------------------------------------------------------------
__global__ __launch_bounds__(256)
void head_conv(const float* __restrict__ body,
               const float* __restrict__ w1, const float* __restrict__ w2,
               const float* __restrict__ w3,
               const float* __restrict__ b1, const float* __restrict__ b2,
               const float* __restrict__ b3,
               float* __restrict__ h, float* __restrict__ g, int b)
{
    constexpr int TW = 32, TH = 32, CHUNK = 8, CIN = 32, COUT = 12;
    constexpr int IW = TW + 2, IWP = TW + 3, IH = TH + 2;
    __shared__ __align__(16) float s_in[CHUNK][IH][IWP];
    __shared__ __align__(16) float s_w[CHUNK][9][COUT];
    __shared__ float s_red[4][12];

    const int tid = threadIdx.x;
    const int ty  = tid >> 3;
    const int tx  = (tid & 7) << 2;
    const int tileX = blockIdx.x * TW;
    const int tileY = blockIdx.y * TH;

    float acc[4][12];
    #pragma unroll
    for (int p = 0; p < 4; ++p)
        #pragma unroll
        for (int i = 0; i < 12; ++i) acc[p][i] = 0.f;

    for (int c0 = 0; c0 < CIN; c0 += CHUNK) {
        for (int idx = tid; idx < CHUNK * IH * IW; idx += 256) {
            int ci = idx / (IH * IW);
            int r  = idx % (IH * IW);
            int iy = r / IW, ix = r % IW;
            int gy = tileY + iy - 1, gx = tileX + ix - 1;
            float v = 0.f;
            if ((unsigned)gy < 512u && (unsigned)gx < 512u)
                v = body[(size_t)(c0 + ci) * HWSZ + gy * 512 + gx];
            s_in[ci][iy][ix] = v;
        }
        for (int idx = tid; idx < CHUNK * 9 * COUT; idx += 256) {
            int ci  = idx / (9 * COUT);
            int r   = idx % (9 * COUT);
            int tap = r / COUT, co = r % COUT;
            int hd = co >> 2, cl = co & 3;
            const float* wp = hd == 0 ? w1 : (hd == 1 ? w2 : w3);
            s_w[ci][tap][co] = wp[((size_t)cl * CIN + (c0 + ci)) * 9 + tap];
        }
        __syncthreads();
        #pragma unroll 1
        for (int ci = 0; ci < CHUNK; ++ci) {
            #pragma unroll
            for (int tap = 0; tap < 9; ++tap) {
                const int dy = tap / 3, dx = tap % 3;
                float iv[4];
                #pragma unroll
                for (int p = 0; p < 4; ++p) iv[p] = s_in[ci][ty + dy][tx + dx + p];
                #pragma unroll
                for (int i = 0; i < 12; i += 4) {
                    const float4 wv = *(const float4*)&s_w[ci][tap][i];
                    #pragma unroll
                    for (int p = 0; p < 4; ++p) {
                        acc[p][i + 0] = fmaf(iv[p], wv.x, acc[p][i + 0]);
                        acc[p][i + 1] = fmaf(iv[p], wv.y, acc[p][i + 1]);
                        acc[p][i + 2] = fmaf(iv[p], wv.z, acc[p][i + 2]);
                        acc[p][i + 3] = fmaf(iv[p], wv.w, acc[p][i + 3]);
                    }
                }
            }
        }
        __syncthreads();
    }

    const int gy = tileY + ty, gx = tileX + tx;
    float psum[12];
    #pragma unroll
    for (int co = 0; co < 12; ++co) {
        int hd = co >> 2, cl = co & 3;
        const float* bp = hd == 0 ? b1 : (hd == 1 ? b2 : b3);
        float bs = bp[cl];
        float4 o;
        o.x = acc[0][co] + bs; o.y = acc[1][co] + bs;
        o.z = acc[2][co] + bs; o.w = acc[3][co] + bs;
        psum[co] = o.x + o.y + o.z + o.w;
        *(float4*)&h[(size_t)((hd * 8 + b) * 4 + cl) * HWSZ + gy * 512 + gx] = o;
    }
    #pragma unroll
    for (int co = 0; co < 12; ++co) {
        #pragma unroll
        for (int off = 32; off >= 1; off >>= 1)
            psum[co] += __shfl_down(psum[co], off);
    }
    const int lane = tid & 63, wv = tid >> 6;
    if (lane == 0) {
        #pragma unroll
        for (int co = 0; co < 12; ++co) s_red[wv][co] = psum[co];
    }
    __syncthreads();
    if (tid < 12) {
        float t = s_red[0][tid] + s_red[1][tid] + s_red[2][tid] + s_red[3][tid];
        atomicAdd(&g[(tid >> 2) * 32 + b * 4 + (tid & 3)], t);
    }
}

// ---------------------------------------------------------------------------
__global__ void zero_k(float* p, int n)
{
    int i = blockIdx.x * 256 + threadIdx.x;
    if (i < n) p[i] = 0.f;
}

__global__ void ca_kernel(const float* __restrict__ g,
                          const float* __restrict__ c11, const float* __restrict__ c12,
                          const float* __restrict__ c21, const float* __restrict__ c22,
                          const float* __restrict__ c31, const float* __restrict__ c32,
                          float* __restrict__ sOut)
{
    int t = threadIdx.x;
    if (t >= 24) return;
    int head = t / 8, b = t % 8;
    const float* c1 = head == 0 ? c11 : (head == 1 ? c21 : c31);
    const float* c2 = head == 0 ? c12 : (head == 1 ? c22 : c32);
    float m[4], v[4];
    #pragma unroll
    for (int i = 0; i < 4; ++i) m[i] = g[head * 32 + b * 4 + i] * (1.0f / 262144.0f);
    #pragma unroll
    for (int j = 0; j < 4; ++j) {
        float x = c1[j*4+0]*m[0] + c1[j*4+1]*m[1] + c1[j*4+2]*m[2] + c1[j*4+3]*m[3];
        v[j] = fmaxf(x, 0.f);
    }
    #pragma unroll
    for (int j = 0; j < 4; ++j) {
        float x = c2[j*4+0]*v[0] + c2[j*4+1]*v[1] + c2[j*4+2]*v[2] + c2[j*4+3]*v[3];
        sOut[head * 32 + b * 4 + j] = 1.f / (1.f + __expf(-x));
    }
}

// ---------------------------------------------------------------------------
__global__ __launch_bounds__(256)
void sat_row(const float* __restrict__ src, float* __restrict__ S)
{
    const int y  = blockIdx.x;
    const int bc = blockIdx.y;
    float* Sp = S + (size_t)bc * 263169;
    const int tid = threadIdx.x;
    if (y == 0) {
        for (int i = tid; i < 513; i += 256) Sp[i] = 0.f;
        return;
    }
    const float2* row2 = (const float2*)(src + (size_t)bc * HWSZ + (size_t)(y - 1) * 512);
    float2 ab = row2[tid];
    float ps = ab.x + ab.y;
    float v = ps;
    const int lane = tid & 63;
    #pragma unroll
    for (int off = 1; off < 64; off <<= 1) {
        float u = __shfl_up(v, off);
        if (lane >= off) v += u;
    }
    __shared__ float wsum[4];
    const int wv = tid >> 6;
    if (lane == 63) wsum[wv] = v;
    __syncthreads();
    float woff = 0.f;
    #pragma unroll
    for (int k = 0; k < 4; ++k) if (k < wv) woff += wsum[k];
    float excl = woff + v - ps;
    float* o = Sp + (size_t)y * 513;
    if (tid == 0) o[0] = 0.f;
    o[1 + 2 * tid] = excl + ab.x;
    o[2 + 2 * tid] = excl + ab.x + ab.y;
}

__global__ __launch_bounds__(512)
void sat_col(float* __restrict__ S)
{
    float* Sp = S + (size_t)blockIdx.x * 263169 + threadIdx.x + 1;
    float run = 0.f;
    for (int i = 1; i <= 512; ++i) {
        float* p = Sp + (size_t)i * 513;
        run += *p;
        *p = run;
    }
}

__device__ __forceinline__ float boxsum(const float* __restrict__ S, int y, int x, int p)
{
    int y0 = max(y - p, 0), x0 = max(x - p, 0);
    int y1 = min(y + p, 511) + 1, x1 = min(x + p, 511) + 1;
    return S[y1 * 513 + x1] - S[y0 * 513 + x1] - S[y1 * 513 + x0] + S[y0 * 513 + x0];
}

__global__ __launch_bounds__(256)
void fuse_kernel(const float* __restrict__ cur, const float* __restrict__ h,
                 const float* __restrict__ sv, const float* __restrict__ S,
                 float* __restrict__ out, int head)
{
    const int idx = blockIdx.x * 256 + threadIdx.x;
    const int b   = idx >> 18;
    const int rem = idx & 262143;
    const int y   = rem >> 9;
    const int x   = rem & 511;

    const float* sp = sv + head * 32 + b * 4;
    const float* hp = h + (size_t)((head * 8 + b) * 4) * HWSZ + rem;
    float z0 = hp[0]          * sp[0];
    float z1 = hp[HWSZ]       * sp[1];
    float z2 = hp[2 * HWSZ]   * sp[2];
    float z3 = hp[3 * HWSZ]   * sp[3];
    float m  = fmaxf(fmaxf(z0, z1), fmaxf(z2, z3));
    float e0 = __expf(z0 - m), e1 = __expf(z1 - m), e2 = __expf(z2 - m), e3 = __expf(z3 - m);
    float inv = 1.f / (e0 + e1 + e2 + e3);
    float p0 = e0 * inv, p1 = e1 * inv, p2 = e2 * inv, p3 = e3 * inv;

    #pragma unroll
    for (int c = 0; c < 3; ++c) {
        const float* Sp = S + (size_t)(b * 3 + c) * 263169;
        float xv = cur[((size_t)b * 3 + c) * HWSZ + rem];
        float m2 = boxsum(Sp, y, x, 2)  * (1.f / 25.f);
        float m3 = boxsum(Sp, y, x, 7)  * (1.f / 225.f);
        float m4 = boxsum(Sp, y, x, 12) * (1.f / 625.f);
        out[((size_t)b * 3 + c) * HWSZ + rem] = p0 * xv + p1 * m2 + p2 * m3 + p3 * m4;
    }
}

// ---------------------------------------------------------------------------
// Workspace (floats): t1 8,388,608 | t2 16,777,216 | hbuf 25,165,824
// | gbuf 96 | sbuf 96 | packed bf16 weights 55,296  ->  ~201.5 MB total
// ---------------------------------------------------------------------------
extern "C" void kernel_launch(void* const* d_in, const int* in_sizes, int n_in,
                              void* d_out, int out_size, void* d_ws, size_t ws_size,
                              hipStream_t stream)
{
    (void)in_sizes; (void)n_in; (void)out_size; (void)ws_size;
    const float* x    = (const float*)d_in[0];
    const float* bw1  = (const float*)d_in[1];
    const float* bb1  = (const float*)d_in[2];
    const float* a1   = (const float*)d_in[3];
    const float* bw2  = (const float*)d_in[4];
    const float* bb2  = (const float*)d_in[5];
    const float* a2   = (const float*)d_in[6];
    const float* bw3  = (const float*)d_in[7];
    const float* bb3  = (const float*)d_in[8];
    const float* a3   = (const float*)d_in[9];
    const float* h1w  = (const float*)d_in[10];
    const float* h1b  = (const float*)d_in[11];
    const float* h1c1 = (const float*)d_in[12];
    const float* h1c2 = (const float*)d_in[13];
    const float* h2w  = (const float*)d_in[14];
    const float* h2b  = (const float*)d_in[15];
    const float* h2c1 = (const float*)d_in[16];
    const float* h2c2 = (const float*)d_in[17];
    const float* h3w  = (const float*)d_in[18];
    const float* h3b  = (const float*)d_in[19];
    const float* h3c1 = (const float*)d_in[20];
    const float* h3c2 = (const float*)d_in[21];

    float* ws   = (float*)d_ws;
    float* t1   = ws;
    float* t2   = t1 + 8388608;
    float* hbuf = t2 + 16777216;
    float* gbuf = hbuf + 25165824;
    float* sbuf = gbuf + 96;
    unsigned short* w2h = (unsigned short*)(sbuf + 96);
    unsigned short* w2l = w2h + 18432;
    unsigned short* w3h = w2l + 18432;
    unsigned short* w3l = w3h + 18432;
    float* SAT  = t2;                  // alias (6,316,056 <= 16,777,216)
    float* ping = t1;                  // alias (6,291,456 <=  8,388,608)

    dim3 blk(256);

    prep_weights<<<dim3(144), blk, 0, stream>>>(bw2, bw3, w2h, w2l, w3h, w3l);
    zero_k<<<dim3(1), dim3(128), 0, stream>>>(gbuf, 96);

    // per-batch body pipeline: x[b] -> t1 -> t2 -> t1 -> heads
    for (int b = 0; b < 8; ++b) {
        conv3x3_prelu<3, 32, 3, 32, 16, 16, 4>
            <<<dim3(16, 32, 1), blk, 0, stream>>>(x + (size_t)b * 3 * HWSZ,
                                                  bw1, bb1, a1, t1);
        conv3x3_mfma<32, 64>
            <<<dim3(8, 256), blk, 0, stream>>>(t1, w2h, w2l, bb2, a2, t2);
        conv3x3_mfma<64, 32>
            <<<dim3(8, 256), blk, 0, stream>>>(t2, w3h, w3l, bb3, a3, t1);
        head_conv<<<dim3(16, 16, 1), blk, 0, stream>>>(t1, h1w, h2w, h3w,
                                                       h1b, h2b, h3b, hbuf, gbuf, b);
    }

    ca_kernel<<<dim3(1), dim3(64), 0, stream>>>(gbuf, h1c1, h1c2, h2c1, h2c2,
                                                h3c1, h3c2, sbuf);

    // fuse chain: x -> ping -> ping(in place) -> d_out
    const float* cur = x;
    for (int i = 0; i < 3; ++i) {
        sat_row<<<dim3(513, 24), blk, 0, stream>>>(cur, SAT);
        sat_col<<<dim3(24), dim3(512), 0, stream>>>(SAT);
        float* nxt = (i == 2) ? (float*)d_out : ping;
        fuse_kernel<<<dim3(8192), blk, 0, stream>>>(cur, hbuf, sbuf, SAT, nxt, i);
        cur = nxt;
    }
}

// Round 5
// 1429.846 us; speedup vs baseline: 2.4153x; 1.7265x over previous
//
#include <hip/hip_runtime.h>
#include <math.h>

#define HWSZ (512*512)

typedef unsigned int u32;
typedef __attribute__((ext_vector_type(8))) short short8;
typedef __attribute__((ext_vector_type(4))) float f32x4;

__device__ __forceinline__ unsigned short f2bf(float f) {
    unsigned u = __float_as_uint(f);
    unsigned r = (u + 0x7FFFu + ((u >> 16) & 1u)) >> 16;
    return (unsigned short)r;
}
__device__ __forceinline__ float bf2f(unsigned short h) {
    return __uint_as_float((unsigned)h << 16);
}
__device__ __forceinline__ u32 packhl(float v) {
    unsigned short h = f2bf(v);
    unsigned short l = f2bf(v - bf2f(h));
    return (u32)h | ((u32)l << 16);
}

// LDS tile geometry for MFMA convs: 6 rows x 72 cols x 32 ci, hi/lo planes.
// granule (8 ci) stride GRAN=3464 shorts (6928 B == 4 banks mod 32): even bank
// spread for both staging b128 writes and fragment b128 reads.
#define GRAN  3464
#define APLANE (4 * GRAN)   // 13856 shorts per plane

// ---------------------------------------------------------------------------
// Weight prep: fp32 OIHW -> [tap][co][ci] bf16 hi/lo (Markidis split).
// conv2 (64x32), conv3 (32x64), heads packed+padded to 16 co (12 valid).
// ---------------------------------------------------------------------------
__global__ void prep_weights(const float* __restrict__ w2, const float* __restrict__ w3,
                             const float* __restrict__ hw1, const float* __restrict__ hw2,
                             const float* __restrict__ hw3,
                             const float* __restrict__ hb1, const float* __restrict__ hb2,
                             const float* __restrict__ hb3,
                             unsigned short* __restrict__ w2h, unsigned short* __restrict__ w2l,
                             unsigned short* __restrict__ w3h, unsigned short* __restrict__ w3l,
                             unsigned short* __restrict__ whh, unsigned short* __restrict__ whl,
                             float* __restrict__ hb16)
{
    int i = blockIdx.x * 256 + threadIdx.x;
    if (i < 18432) {
        int tap = i / 2048, r = i % 2048, co = r / 32, ci = r % 32;
        float v = w2[((co * 32 + ci) * 9) + tap];
        unsigned short h = f2bf(v);
        w2h[i] = h; w2l[i] = f2bf(v - bf2f(h));
    } else if (i < 36864) {
        int e = i - 18432;
        int tap = e / 2048, r = e % 2048, co = r / 64, ci = r % 64;
        float v = w3[((co * 64 + ci) * 9) + tap];
        unsigned short h = f2bf(v);
        w3h[e] = h; w3l[e] = f2bf(v - bf2f(h));
    } else if (i < 41472) {
        int e = i - 36864;
        int tap = e / 512, r = e % 512, co16 = r / 32, ci = r % 32;
        float v = 0.f;
        if (co16 < 12) {
            int hd = co16 >> 2, cl = co16 & 3;
            const float* wp = hd == 0 ? hw1 : (hd == 1 ? hw2 : hw3);
            v = wp[((cl * 32 + ci) * 9) + tap];
        }
        unsigned short h = f2bf(v);
        whh[e] = h; whl[e] = f2bf(v - bf2f(h));
    } else if (i < 41488) {
        int j = i - 41472;
        float v = 0.f;
        if (j < 12) {
            const float* bp = (j >> 2) == 0 ? hb1 : ((j >> 2) == 1 ? hb2 : hb3);
            v = bp[j & 3];
        }
        hb16[j] = v;
    }
}

// ---------------------------------------------------------------------------
// Stage 6x72(66 used)xCIN-chunk tile from packed hi/lo NHWC global into LDS.
// Wave lanes: 16 cols x 4 ci-granules -> 2 KB contiguous global per instr.
// ---------------------------------------------------------------------------
template<int CIN>
__device__ __forceinline__ void stage_tile(const u32* __restrict__ in,
                                           unsigned short* s_a,
                                           int w, int lane, int x1, int y0, int c0)
{
    const int c16 = lane & 15;
    const int g   = lane >> 4;
    for (int it = w; it < 30; it += 4) {
        int r  = it / 5;
        int cb = it % 5;
        int col = cb * 16 + c16;
        if (col < 66) {
            int gy = y0 - 1 + r;
            int gx = x1 - 1 + col;
            u32 d0=0,d1=0,d2=0,d3=0,d4=0,d5=0,d6=0,d7=0;
            if ((unsigned)gy < 512u && (unsigned)gx < 512u) {
                const uint4* p = (const uint4*)(in + ((size_t)(gy * 512 + gx)) * CIN + c0 + g * 8);
                uint4 A = p[0], B = p[1];
                d0=A.x; d1=A.y; d2=A.z; d3=A.w; d4=B.x; d5=B.y; d6=B.z; d7=B.w;
            }
            uint4 hi, lo;
            hi.x = (d0 & 0xffffu) | (d1 << 16);
            hi.y = (d2 & 0xffffu) | (d3 << 16);
            hi.z = (d4 & 0xffffu) | (d5 << 16);
            hi.w = (d6 & 0xffffu) | (d7 << 16);
            lo.x = (d0 >> 16) | (d1 & 0xffff0000u);
            lo.y = (d2 >> 16) | (d3 & 0xffff0000u);
            lo.z = (d4 >> 16) | (d5 & 0xffff0000u);
            lo.w = (d6 >> 16) | (d7 & 0xffff0000u);
            int e = (r * 72 + col) * 8;
            *(uint4*)(s_a + g * GRAN + e) = hi;
            *(uint4*)(s_a + APLANE + g * GRAN + e) = lo;
        }
    }
}

// ---------------------------------------------------------------------------
// 3x3 conv + bias + PReLU, NHWC hi/lo packed in/out, bf16 MFMA 3-pass.
// Tile: 4 rows x 64 cols x COUT. 4 waves x 4 m-tiles; NTW n-tiles per wave.
// ---------------------------------------------------------------------------
template<int CIN, int COUT>
__global__ __launch_bounds__(256, 2)
void conv_mfma(const u32* __restrict__ in,
               const unsigned short* __restrict__ wh,
               const unsigned short* __restrict__ wl,
               const float* __restrict__ bias,
               const float* __restrict__ alpha,
               u32* __restrict__ out)
{
    constexpr int NTW = COUT / 16;
    __shared__ __align__(16) unsigned short s_a[2 * APLANE];

    const int tid  = threadIdx.x;
    const int w    = tid >> 6;
    const int lane = tid & 63;
    const int ln   = lane & 15;
    const int quad = lane >> 4;
    const int x1   = blockIdx.x * 64;
    const int y0   = blockIdx.y * 4;

    f32x4 acc[4][NTW];
    #pragma unroll
    for (int mt = 0; mt < 4; ++mt)
        #pragma unroll
        for (int nt = 0; nt < NTW; ++nt)
            acc[mt][nt] = (f32x4){0.f, 0.f, 0.f, 0.f};

    for (int c0 = 0; c0 < CIN; c0 += 32) {
        if (c0) __syncthreads();
        stage_tile<CIN>(in, s_a, w, lane, x1, y0, c0);
        __syncthreads();

        #pragma unroll
        for (int tap = 0; tap < 9; ++tap) {
            const int dy = tap / 3, dx = tap % 3;
            short8 bh[NTW], bl[NTW];
            #pragma unroll
            for (int nt = 0; nt < NTW; ++nt) {
                size_t off = ((size_t)(tap * COUT + nt * 16 + ln)) * CIN + c0 + quad * 8;
                bh[nt] = *(const short8*)(wh + off);
                bl[nt] = *(const short8*)(wl + off);
            }
            short8 ah[4], al[4];
            #pragma unroll
            for (int mt = 0; mt < 4; ++mt) {
                const int mti = w * 4 + mt;
                const int rr  = (mti >> 2) + dy;
                const int col = ((mti & 3) << 4) + ln + dx;
                const int off = quad * GRAN + (rr * 72 + col) * 8;
                ah[mt] = *(const short8*)(s_a + off);
                al[mt] = *(const short8*)(s_a + APLANE + off);
            }
            #pragma unroll
            for (int mt = 0; mt < 4; ++mt)
                #pragma unroll
                for (int nt = 0; nt < NTW; ++nt)
                    acc[mt][nt] = __builtin_amdgcn_mfma_f32_16x16x32_bf16(ah[mt], bh[nt], acc[mt][nt], 0, 0, 0);
            #pragma unroll
            for (int mt = 0; mt < 4; ++mt)
                #pragma unroll
                for (int nt = 0; nt < NTW; ++nt)
                    acc[mt][nt] = __builtin_amdgcn_mfma_f32_16x16x32_bf16(al[mt], bh[nt], acc[mt][nt], 0, 0, 0);
            #pragma unroll
            for (int mt = 0; mt < 4; ++mt)
                #pragma unroll
                for (int nt = 0; nt < NTW; ++nt)
                    acc[mt][nt] = __builtin_amdgcn_mfma_f32_16x16x32_bf16(ah[mt], bl[nt], acc[mt][nt], 0, 0, 0);
        }
    }

    const float av = alpha[0];
    float bs[NTW];
    #pragma unroll
    for (int nt = 0; nt < NTW; ++nt) bs[nt] = bias[nt * 16 + ln];
    #pragma unroll
    for (int mt = 0; mt < 4; ++mt) {
        const int mti = w * 4 + mt;
        const int y   = y0 + (mti >> 2);
        const int xb  = x1 + ((mti & 3) << 4) + quad * 4;
        #pragma unroll
        for (int nt = 0; nt < NTW; ++nt) {
            const int co = nt * 16 + ln;
            #pragma unroll
            for (int reg = 0; reg < 4; ++reg) {
                float t = acc[mt][nt][reg] + bs[nt];
                t = t > 0.f ? t : av * t;
                out[((size_t)(y * 512 + xb + reg)) * COUT + co] = packhl(t);
            }
        }
    }
}

// ---------------------------------------------------------------------------
// Head conv: 32 -> 16 co (12 valid = 3 heads x 4), MFMA 3-pass, + GAP atomics.
// Writes h planes NCHW fp32 via LDS transpose (coalesced 64-B segments).
// ---------------------------------------------------------------------------
__global__ __launch_bounds__(256, 2)
void head_mfma(const u32* __restrict__ in,
               const unsigned short* __restrict__ wh,
               const unsigned short* __restrict__ wl,
               const float* __restrict__ hb,
               float* __restrict__ h, float* __restrict__ g2, int b)
{
    __shared__ __align__(16) unsigned short s_a[2 * APLANE];
    __shared__ float s_red[4][16];

    const int tid  = threadIdx.x;
    const int w    = tid >> 6;
    const int lane = tid & 63;
    const int ln   = lane & 15;
    const int quad = lane >> 4;
    const int x1   = blockIdx.x * 64;
    const int y0   = blockIdx.y * 4;

    f32x4 acc[4];
    #pragma unroll
    for (int mt = 0; mt < 4; ++mt) acc[mt] = (f32x4){0.f, 0.f, 0.f, 0.f};

    stage_tile<32>(in, s_a, w, lane, x1, y0, 0);
    __syncthreads();

    #pragma unroll
    for (int tap = 0; tap < 9; ++tap) {
        const int dy = tap / 3, dx = tap % 3;
        size_t boff = (size_t)tap * 512 + ln * 32 + quad * 8;
        short8 bh = *(const short8*)(wh + boff);
        short8 bl = *(const short8*)(wl + boff);
        short8 ah[4], al[4];
        #pragma unroll
        for (int mt = 0; mt < 4; ++mt) {
            const int mti = w * 4 + mt;
            const int rr  = (mti >> 2) + dy;
            const int col = ((mti & 3) << 4) + ln + dx;
            const int off = quad * GRAN + (rr * 72 + col) * 8;
            ah[mt] = *(const short8*)(s_a + off);
            al[mt] = *(const short8*)(s_a + APLANE + off);
        }
        #pragma unroll
        for (int mt = 0; mt < 4; ++mt)
            acc[mt] = __builtin_amdgcn_mfma_f32_16x16x32_bf16(ah[mt], bh, acc[mt], 0, 0, 0);
        #pragma unroll
        for (int mt = 0; mt < 4; ++mt)
            acc[mt] = __builtin_amdgcn_mfma_f32_16x16x32_bf16(al[mt], bh, acc[mt], 0, 0, 0);
        #pragma unroll
        for (int mt = 0; mt < 4; ++mt)
            acc[mt] = __builtin_amdgcn_mfma_f32_16x16x32_bf16(ah[mt], bl, acc[mt], 0, 0, 0);
    }

    __syncthreads();                       // s_a reads done; reuse as s_h
    float* s_h = (float*)s_a;              // [12][260]
    const float bs = hb[ln];
    float psum = 0.f;
    #pragma unroll
    for (int mt = 0; mt < 4; ++mt) {
        const int mti  = w * 4 + mt;
        const int base = (mti >> 2) * 64 + ((mti & 3) << 4) + quad * 4;
        #pragma unroll
        for (int reg = 0; reg < 4; ++reg) {
            float v = acc[mt][reg] + bs;
            if (ln < 12) s_h[ln * 260 + base + reg] = v;
            psum += v;                     // lanes >= 12: weights+bias zero -> 0
        }
    }
    psum += __shfl_down(psum, 16);
    psum += __shfl_down(psum, 32);
    if (lane < 16) s_red[w][lane] = psum;
    __syncthreads();

    if (tid < 192) {
        const int co = tid >> 4, ch = tid & 15;
        const float* src = s_h + co * 260 + ch * 16;
        float4 v0 = *(const float4*)(src);
        float4 v1 = *(const float4*)(src + 4);
        float4 v2 = *(const float4*)(src + 8);
        float4 v3 = *(const float4*)(src + 12);
        const int hd = co >> 2, cl = co & 3;
        float* dst = h + ((size_t)((hd * 8 + b) * 4 + cl)) * HWSZ
                       + (size_t)(y0 + (ch >> 2)) * 512 + x1 + ((ch & 3) << 4);
        *(float4*)(dst)      = v0;
        *(float4*)(dst + 4)  = v1;
        *(float4*)(dst + 8)  = v2;
        *(float4*)(dst + 12) = v3;
    }
    if (tid < 12) {
        float t = s_red[0][tid] + s_red[1][tid] + s_red[2][tid] + s_red[3][tid];
        atomicAdd(&g2[(tid >> 2) * 32 + b * 4 + (tid & 3)], t);
    }
}

// ---------------------------------------------------------------------------
// conv1: 3 -> 32, fp32 direct, thread-per-pixel, writes packed NHWC.
// ---------------------------------------------------------------------------
__global__ __launch_bounds__(256)
void conv1_nhwc(const float* __restrict__ x, const float* __restrict__ wgt,
                const float* __restrict__ bias, const float* __restrict__ alpha,
                u32* __restrict__ out)
{
    __shared__ float s_in[3][6][72];
    __shared__ float s_w[3][9][32];
    __shared__ float s_b[32];
    const int tid = threadIdx.x;
    const int x1 = blockIdx.x * 64, y0 = blockIdx.y * 4;

    for (int i = tid; i < 3 * 6 * 66; i += 256) {
        int ci = i / 396, rm = i % 396;
        int r = rm / 66, cc = rm % 66;
        int gy = y0 - 1 + r, gx = x1 - 1 + cc;
        float v = 0.f;
        if ((unsigned)gy < 512u && (unsigned)gx < 512u)
            v = x[(size_t)ci * HWSZ + gy * 512 + gx];
        s_in[ci][r][cc] = v;
    }
    for (int i = tid; i < 864; i += 256) {
        int co = i & 31, rm = i >> 5;
        int ci = rm / 9, tap = rm % 9;
        s_w[ci][tap][co] = wgt[(co * 3 + ci) * 9 + tap];
    }
    if (tid < 32) s_b[tid] = bias[tid];
    __syncthreads();

    const int ty = tid >> 6, tx = tid & 63;
    float acc[32];
    #pragma unroll
    for (int i = 0; i < 32; ++i) acc[i] = 0.f;
    #pragma unroll
    for (int ci = 0; ci < 3; ++ci)
        #pragma unroll
        for (int tap = 0; tap < 9; ++tap) {
            const int dy = tap / 3, dx = tap % 3;
            float iv = s_in[ci][ty + dy][tx + dx];
            #pragma unroll
            for (int c4 = 0; c4 < 8; ++c4) {
                float4 wv = *(const float4*)&s_w[ci][tap][c4 * 4];
                acc[c4*4+0] = fmaf(iv, wv.x, acc[c4*4+0]);
                acc[c4*4+1] = fmaf(iv, wv.y, acc[c4*4+1]);
                acc[c4*4+2] = fmaf(iv, wv.z, acc[c4*4+2]);
                acc[c4*4+3] = fmaf(iv, wv.w, acc[c4*4+3]);
            }
        }
    const float av = alpha[0];
    u32* o = out + ((size_t)((y0 + ty) * 512 + x1 + tx)) * 32;
    #pragma unroll
    for (int c4 = 0; c4 < 8; ++c4) {
        uint4 pk;
        float t;
        t = acc[c4*4+0] + s_b[c4*4+0]; t = t > 0.f ? t : av * t; pk.x = packhl(t);
        t = acc[c4*4+1] + s_b[c4*4+1]; t = t > 0.f ? t : av * t; pk.y = packhl(t);
        t = acc[c4*4+2] + s_b[c4*4+2]; t = t > 0.f ? t : av * t; pk.z = packhl(t);
        t = acc[c4*4+3] + s_b[c4*4+3]; t = t > 0.f ? t : av * t; pk.w = packhl(t);
        *(uint4*)(o + c4 * 4) = pk;
    }
}

// ---------------------------------------------------------------------------
__global__ void zero_k(float* p, int n)
{
    int i = blockIdx.x * 256 + threadIdx.x;
    if (i < n) p[i] = 0.f;
}

__global__ void ca_kernel(const float* __restrict__ g,
                          const float* __restrict__ c11, const float* __restrict__ c12,
                          const float* __restrict__ c21, const float* __restrict__ c22,
                          const float* __restrict__ c31, const float* __restrict__ c32,
                          float* __restrict__ sOut)
{
    int t = threadIdx.x;
    if (t >= 24) return;
    int head = t / 8, b = t % 8;
    const float* c1 = head == 0 ? c11 : (head == 1 ? c21 : c31);
    const float* c2 = head == 0 ? c12 : (head == 1 ? c22 : c32);
    float m[4], v[4];
    #pragma unroll
    for (int i = 0; i < 4; ++i) m[i] = g[head * 32 + b * 4 + i] * (1.0f / 262144.0f);
    #pragma unroll
    for (int j = 0; j < 4; ++j) {
        float xv = c1[j*4+0]*m[0] + c1[j*4+1]*m[1] + c1[j*4+2]*m[2] + c1[j*4+3]*m[3];
        v[j] = fmaxf(xv, 0.f);
    }
    #pragma unroll
    for (int j = 0; j < 4; ++j) {
        float xv = c2[j*4+0]*v[0] + c2[j*4+1]*v[1] + c2[j*4+2]*v[2] + c2[j*4+3]*v[3];
        sOut[head * 32 + b * 4 + j] = 1.f / (1.f + __expf(-xv));
    }
}

// ---------------------------------------------------------------------------
// Integral image (SAT): 513x513 per (b,c) plane.
// ---------------------------------------------------------------------------
__global__ __launch_bounds__(256)
void sat_row(const float* __restrict__ src, float* __restrict__ S)
{
    const int y  = blockIdx.x;
    const int bc = blockIdx.y;
    float* Sp = S + (size_t)bc * 263169;
    const int tid = threadIdx.x;
    if (y == 0) {
        for (int i = tid; i < 513; i += 256) Sp[i] = 0.f;
        return;
    }
    const float2* row2 = (const float2*)(src + (size_t)bc * HWSZ + (size_t)(y - 1) * 512);
    float2 ab = row2[tid];
    float ps = ab.x + ab.y;
    float v = ps;
    const int lane = tid & 63;
    #pragma unroll
    for (int off = 1; off < 64; off <<= 1) {
        float u = __shfl_up(v, off);
        if (lane >= off) v += u;
    }
    __shared__ float wsum[4];
    const int wv = tid >> 6;
    if (lane == 63) wsum[wv] = v;
    __syncthreads();
    float woff = 0.f;
    #pragma unroll
    for (int k = 0; k < 4; ++k) if (k < wv) woff += wsum[k];
    float excl = woff + v - ps;
    float* o = Sp + (size_t)y * 513;
    if (tid == 0) o[0] = 0.f;
    o[1 + 2 * tid] = excl + ab.x;
    o[2 + 2 * tid] = excl + ab.x + ab.y;
}

// column scan: grid (24, 2) x 256 thr; 16-deep manual unroll keeps 16 loads
// in flight per thread (dependency is only the running sum).
__global__ __launch_bounds__(256)
void sat_col(float* __restrict__ S)
{
    const int bc = blockIdx.x;
    const int c  = 1 + blockIdx.y * 256 + threadIdx.x;   // 1..512
    float* P = S + (size_t)bc * 263169 + c;
    float run = 0.f;
    for (int r0 = 1; r0 <= 512; r0 += 16) {
        float v[16];
        #pragma unroll
        for (int i = 0; i < 16; ++i) v[i] = P[(size_t)(r0 + i) * 513];
        #pragma unroll
        for (int i = 0; i < 16; ++i) { run += v[i]; v[i] = run; }
        #pragma unroll
        for (int i = 0; i < 16; ++i) P[(size_t)(r0 + i) * 513] = v[i];
    }
}

__device__ __forceinline__ float boxsum(const float* __restrict__ S, int y, int x, int p)
{
    int y0 = max(y - p, 0), x0 = max(x - p, 0);
    int y1 = min(y + p, 511) + 1, x1 = min(x + p, 511) + 1;
    return S[y1 * 513 + x1] - S[y0 * 513 + x1] - S[y1 * 513 + x0] + S[y0 * 513 + x0];
}

__global__ __launch_bounds__(256)
void fuse_kernel(const float* __restrict__ cur, const float* __restrict__ h,
                 const float* __restrict__ sv, const float* __restrict__ S,
                 float* __restrict__ out, int head)
{
    const int idx = blockIdx.x * 256 + threadIdx.x;
    const int b   = idx >> 18;
    const int rem = idx & 262143;
    const int y   = rem >> 9;
    const int x   = rem & 511;

    const float* sp = sv + head * 32 + b * 4;
    const float* hp = h + (size_t)((head * 8 + b) * 4) * HWSZ + rem;
    float z0 = hp[0]          * sp[0];
    float z1 = hp[HWSZ]       * sp[1];
    float z2 = hp[2 * HWSZ]   * sp[2];
    float z3 = hp[3 * HWSZ]   * sp[3];
    float m  = fmaxf(fmaxf(z0, z1), fmaxf(z2, z3));
    float e0 = __expf(z0 - m), e1 = __expf(z1 - m), e2 = __expf(z2 - m), e3 = __expf(z3 - m);
    float inv = 1.f / (e0 + e1 + e2 + e3);
    float p0 = e0 * inv, p1 = e1 * inv, p2 = e2 * inv, p3 = e3 * inv;

    #pragma unroll
    for (int c = 0; c < 3; ++c) {
        const float* Sp = S + (size_t)(b * 3 + c) * 263169;
        float xv = cur[((size_t)b * 3 + c) * HWSZ + rem];
        float m2 = boxsum(Sp, y, x, 2)  * (1.f / 25.f);
        float m3 = boxsum(Sp, y, x, 7)  * (1.f / 225.f);
        float m4 = boxsum(Sp, y, x, 12) * (1.f / 625.f);
        out[((size_t)b * 3 + c) * HWSZ + rem] = p0 * xv + p1 * m2 + p2 * m3 + p3 * m4;
    }
}

// ---------------------------------------------------------------------------
// Workspace (dwords): t1 8,388,608 | t2 16,777,216 | hbuf 25,165,824
// | gbuf 96 | sbuf 96 | bf16 weights ~83K shorts | hb16 16  -> ~201.6 MB
// ---------------------------------------------------------------------------
extern "C" void kernel_launch(void* const* d_in, const int* in_sizes, int n_in,
                              void* d_out, int out_size, void* d_ws, size_t ws_size,
                              hipStream_t stream)
{
    (void)in_sizes; (void)n_in; (void)out_size; (void)ws_size;
    const float* x    = (const float*)d_in[0];
    const float* bw1  = (const float*)d_in[1];
    const float* bb1  = (const float*)d_in[2];
    const float* a1   = (const float*)d_in[3];
    const float* bw2  = (const float*)d_in[4];
    const float* bb2  = (const float*)d_in[5];
    const float* a2   = (const float*)d_in[6];
    const float* bw3  = (const float*)d_in[7];
    const float* bb3  = (const float*)d_in[8];
    const float* a3   = (const float*)d_in[9];
    const float* h1w  = (const float*)d_in[10];
    const float* h1b  = (const float*)d_in[11];
    const float* h1c1 = (const float*)d_in[12];
    const float* h1c2 = (const float*)d_in[13];
    const float* h2w  = (const float*)d_in[14];
    const float* h2b  = (const float*)d_in[15];
    const float* h2c1 = (const float*)d_in[16];
    const float* h2c2 = (const float*)d_in[17];
    const float* h3w  = (const float*)d_in[18];
    const float* h3b  = (const float*)d_in[19];
    const float* h3c1 = (const float*)d_in[20];
    const float* h3c2 = (const float*)d_in[21];

    float* ws   = (float*)d_ws;
    u32*   t1u  = (u32*)ws;                         //  8,388,608 dwords (NHWC hl32, 32ch)
    u32*   t2u  = t1u + 8388608;                    // 16,777,216 dwords (NHWC hl32, 64ch)
    float* hbuf = (float*)(t2u + 16777216);         // 25,165,824 fl (h NCHW fp32)
    float* gbuf = hbuf + 25165824;                  // 96
    float* sbuf = gbuf + 96;                        // 96
    unsigned short* wb = (unsigned short*)(sbuf + 96);
    unsigned short* w2h = wb;                       // 18432
    unsigned short* w2l = wb + 18432;
    unsigned short* w3h = wb + 36864;
    unsigned short* w3l = wb + 55296;
    unsigned short* whh = wb + 73728;               // 4608
    unsigned short* whl = wb + 78336;
    float* hb16 = (float*)(wb + 82944);             // 16
    float* SAT  = (float*)t2u;                      // alias (6,316,056 <= 16,777,216)
    float* ping = (float*)t1u;                      // alias (6,291,456 <=  8,388,608)

    dim3 blk(256);

    prep_weights<<<dim3(163), blk, 0, stream>>>(bw2, bw3, h1w, h2w, h3w,
                                                h1b, h2b, h3b,
                                                w2h, w2l, w3h, w3l, whh, whl, hb16);
    zero_k<<<dim3(1), dim3(128), 0, stream>>>(gbuf, 96);

    // per-batch body: x[b] -> t1 -> t2 -> t1 -> heads
    for (int b = 0; b < 8; ++b) {
        conv1_nhwc<<<dim3(8, 128), blk, 0, stream>>>(x + (size_t)b * 3 * HWSZ,
                                                     bw1, bb1, a1, t1u);
        conv_mfma<32, 64><<<dim3(8, 128), blk, 0, stream>>>(t1u, w2h, w2l, bb2, a2, t2u);
        conv_mfma<64, 32><<<dim3(8, 128), blk, 0, stream>>>(t2u, w3h, w3l, bb3, a3, t1u);
        head_mfma<<<dim3(8, 128), blk, 0, stream>>>(t1u, whh, whl, hb16, hbuf, gbuf, b);
    }

    ca_kernel<<<dim3(1), dim3(64), 0, stream>>>(gbuf, h1c1, h1c2, h2c1, h2c2,
                                                h3c1, h3c2, sbuf);

    // fuse chain: x -> ping -> ping(in place) -> d_out
    const float* cur = x;
    for (int i = 0; i < 3; ++i) {
        sat_row<<<dim3(513, 24), blk, 0, stream>>>(cur, SAT);
        sat_col<<<dim3(24, 2), blk, 0, stream>>>(SAT);
        float* nxt = (i == 2) ? (float*)d_out : ping;
        fuse_kernel<<<dim3(8192), blk, 0, stream>>>(cur, hbuf, sbuf, SAT, nxt, i);
        cur = nxt;
    }
}